// Round 2
// baseline (2216.899 us; speedup 1.0000x reference)
//
#include <hip/hip_runtime.h>

#define NUM_CAT 16
#define NUM_ATTR 144
#define NUM_NUM 128
#define N_ARY 32
#define NUM_SEG 100000
#define N_ROWS 1000000

// ws layout:
//   int   hdr_i[0..31]  : selcol[j] = 16 + top_num_idx[j] (full-row column)
//   float hdr_f[32..63] : conf[j]
//   int   hdr_i[64]     : topcat (argmax of cat_mask)
//   512              : float agg2[32][NUM_SEG]  12.8 MB (col-major accumulator:
//                      wave's 32 atomics land on 32 DIFFERENT lines, not one)
//   512 + 12.8 MB    : float agg [NUM_SEG][32]  12.8 MB (seg-major, for gather)
//   512 + 25.6 MB    : int   segc[N_ROWS]        4 MB   (compacted seg per row)
#define AGG2_OFFSET 512
#define AGG_OFFSET  (AGG2_OFFSET + (size_t)NUM_SEG * 32 * 4)
#define SEGC_OFFSET (AGG2_OFFSET + 2 * (size_t)NUM_SEG * 32 * 4)

// One block of 128 threads; rank-based parallel top-k (no scratch arrays).
__global__ void setup_kernel(const float* __restrict__ cat_mask,
                             const float* __restrict__ num_mask,
                             int* __restrict__ hdr_i,
                             float* __restrict__ hdr_f) {
    __shared__ float s_cm[NUM_CAT];
    __shared__ float s_x[NUM_NUM];
    __shared__ float s_p[NUM_NUM];
    const int tid = threadIdx.x;            // 0..127

    if (tid < NUM_CAT) s_cm[tid] = cat_mask[tid];
    float x = num_mask[tid];
    s_x[tid] = x;
    __syncthreads();

    // numeric softmax (redundant per-thread reduce; LDS same-addr broadcasts)
    float nmax = s_x[0];
    #pragma unroll 8
    for (int i = 1; i < NUM_NUM; ++i) nmax = fmaxf(nmax, s_x[i]);
    float e = expf(x - nmax);
    s_p[tid] = e;
    __syncthreads();
    float nsum = 0.f;
    #pragma unroll 8
    for (int i = 0; i < NUM_NUM; ++i) nsum += s_p[i];
    float inv = 1.0f / nsum;
    float p = e * inv;
    __syncthreads();
    s_p[tid] = p;                            // normalized probs for ranking
    __syncthreads();

    // cat softmax top-1 (16 elems, registers only)
    float cmax = s_cm[0]; int cidx = 0;
    #pragma unroll
    for (int i = 1; i < NUM_CAT; ++i) {
        float v = s_cm[i];
        if (v > cmax) { cmax = v; cidx = i; }   // strict > : ties -> lower idx
    }
    float csum = 0.f;
    #pragma unroll
    for (int i = 0; i < NUM_CAT; ++i) csum += expf(s_cm[i] - cmax);
    float top_cat_val = 1.0f / csum;

    // rank of this thread's prob among all 128 (descending, stable)
    int rank = 0;
    #pragma unroll 8
    for (int j = 0; j < NUM_NUM; ++j) {
        float pj = s_p[j];
        rank += (pj > p) || (pj == p && j < tid);
    }
    if (rank < N_ARY) {
        hdr_i[rank] = NUM_CAT + tid;
        hdr_f[32 + rank] = 0.5f * (p + top_cat_val);
    }
    if (tid == 0) hdr_i[64] = cidx;
}

// Col-major accumulation: atomicAdd(&agg2[j*NUM_SEG+seg]) — a wave's 32 lanes
// (j=0..31, same seg) hit 32 lines 400 KB apart instead of one 128 B line.
// Lane j==0 also compacts seg into segc[row] for the gather pass.
__global__ void accum_kernel(const float* __restrict__ inputs,
                             const int* __restrict__ idx,
                             const int* __restrict__ hdr_i,
                             float* __restrict__ agg2,
                             int* __restrict__ segc) {
    const int j = threadIdx.x & 31;          // invariant: stride % 32 == 0
    const int col = hdr_i[j];
    const int topcat = hdr_i[64];
    const int total = N_ROWS * 32;
    int t = blockIdx.x * blockDim.x + threadIdx.x;
    const int stride = gridDim.x * blockDim.x;
    for (; t < total; t += stride) {
        int row = t >> 5;
        int seg = idx[row * NUM_CAT + topcat];
        float v = inputs[row * NUM_ATTR + col];
        atomicAdd(&agg2[j * NUM_SEG + seg], v);
        if (j == 0) segc[row] = seg;
    }
}

// agg[seg][j] = agg2[j][seg], LDS-tiled (64 segs x 32 j per block).
// tile stride 65 -> read phase lanes hit distinct banks (stride-65 % 32 bijective).
__global__ void transpose_kernel(const float* __restrict__ agg2,
                                 float* __restrict__ agg) {
    __shared__ float tile[32][64 + 1];
    const int s0 = blockIdx.x * 64;
    const int ts = threadIdx.x & 63;         // seg within tile
    const int tj = threadIdx.x >> 6;         // 0..3
    #pragma unroll
    for (int j = tj; j < 32; j += 4) {
        int s = s0 + ts;
        tile[j][ts] = (s < NUM_SEG) ? agg2[j * NUM_SEG + s] : 0.f;
    }
    __syncthreads();
    const int wj = threadIdx.x & 31;         // j (coalesced 128 B writes per seg)
    const int ws = threadIdx.x >> 5;         // 0..7
    #pragma unroll
    for (int s = ws; s < 64; s += 8) {
        int seg = s0 + s;
        if (seg < NUM_SEG) agg[seg * 32 + wj] = tile[wj][s];
    }
}

__global__ void gather_kernel(const int* __restrict__ segc,
                              const float* __restrict__ hdr_f,
                              const float* __restrict__ agg,
                              float* __restrict__ out) {
    const int j = threadIdx.x & 31;
    const float cf = hdr_f[32 + j];
    const int total = N_ROWS * 32;
    int t = blockIdx.x * blockDim.x + threadIdx.x;
    const int stride = gridDim.x * blockDim.x;
    for (; t < total; t += stride) {
        int row = t >> 5;
        int seg = segc[row];                 // 4 MB compact array, not 64 MB idx
        out[t] = agg[seg * 32 + j] * cf;
    }
}

extern "C" void kernel_launch(void* const* d_in, const int* in_sizes, int n_in,
                              void* d_out, int out_size, void* d_ws, size_t ws_size,
                              hipStream_t stream) {
    const float* inputs   = (const float*)d_in[0];   // (1M, 144) f32
    const int*   idx      = (const int*)d_in[1];     // (1M, 16) int
    const float* cat_mask = (const float*)d_in[2];   // (16,)
    const float* num_mask = (const float*)d_in[3];   // (128,)
    float* out = (float*)d_out;                      // (1M, 32) f32

    int*   hdr_i = (int*)d_ws;
    float* hdr_f = (float*)d_ws;
    float* agg2  = (float*)((char*)d_ws + AGG2_OFFSET);
    float* agg   = (float*)((char*)d_ws + AGG_OFFSET);
    int*   segc  = (int*)((char*)d_ws + SEGC_OFFSET);

    // 1) mask math -> header
    setup_kernel<<<1, 128, 0, stream>>>(cat_mask, num_mask, hdr_i, hdr_f);

    // 2) zero col-major accumulator (memset node is graph-capture safe)
    hipMemsetAsync(agg2, 0, (size_t)NUM_SEG * 32 * sizeof(float), stream);

    // 3) segment-sum of the 32 selected columns (col-major, contention-free)
    accum_kernel<<<8192, 256, 0, stream>>>(inputs, idx, hdr_i, agg2, segc);

    // 4) transpose accumulator to seg-major for contiguous gather reads
    transpose_kernel<<<(NUM_SEG + 63) / 64, 256, 0, stream>>>(agg2, agg);

    // 5) gather + scale
    gather_kernel<<<8192, 256, 0, stream>>>(segc, hdr_f, agg, out);
}

// Round 3
// 1089.040 us; speedup vs baseline: 2.0356x; 2.0356x over previous
//
#include <hip/hip_runtime.h>

#define NUM_CAT 16
#define NUM_ATTR 144
#define NUM_NUM 128
#define N_ARY 32
#define NUM_SEG 100000
#define N_ROWS 1000000

// ws layout:
//   int   hdr_i[0..31]  : selcol[j] = 16 + top_num_idx[j] (full-row column)
//   float hdr_f[32..63] : conf[j]
//   int   hdr_i[64]     : topcat (argmax of cat_mask)
//   1 MB : int cnt[NUM_SEG]   (histogram; after reduce used as count)
//   2 MB : int ofs[NUM_SEG]   (exclusive prefix -> after place: END offsets)
//   4 MB : int segc[N_ROWS]   (compacted seg per row)
//   8 MB : int order[N_ROWS]  (row ids grouped by seg)
#define CNT_OFFSET   (1u << 20)
#define OFS_OFFSET   (2u << 20)
#define SEGC_OFFSET  (4u << 20)
#define ORDER_OFFSET (8u << 20)

// One block of 128 threads; rank-based parallel top-k (no scratch arrays).
__global__ void setup_kernel(const float* __restrict__ cat_mask,
                             const float* __restrict__ num_mask,
                             int* __restrict__ hdr_i,
                             float* __restrict__ hdr_f) {
    __shared__ float s_cm[NUM_CAT];
    __shared__ float s_x[NUM_NUM];
    __shared__ float s_p[NUM_NUM];
    const int tid = threadIdx.x;            // 0..127

    if (tid < NUM_CAT) s_cm[tid] = cat_mask[tid];
    float x = num_mask[tid];
    s_x[tid] = x;
    __syncthreads();

    // numeric softmax (redundant per-thread reduce; LDS same-addr broadcasts)
    float nmax = s_x[0];
    #pragma unroll 8
    for (int i = 1; i < NUM_NUM; ++i) nmax = fmaxf(nmax, s_x[i]);
    float e = expf(x - nmax);
    s_p[tid] = e;
    __syncthreads();
    float nsum = 0.f;
    #pragma unroll 8
    for (int i = 0; i < NUM_NUM; ++i) nsum += s_p[i];
    float inv = 1.0f / nsum;
    float p = e * inv;
    __syncthreads();
    s_p[tid] = p;                            // normalized probs for ranking
    __syncthreads();

    // cat softmax top-1 (16 elems, registers only)
    float cmax = s_cm[0]; int cidx = 0;
    #pragma unroll
    for (int i = 1; i < NUM_CAT; ++i) {
        float v = s_cm[i];
        if (v > cmax) { cmax = v; cidx = i; }   // strict > : ties -> lower idx
    }
    float csum = 0.f;
    #pragma unroll
    for (int i = 0; i < NUM_CAT; ++i) csum += expf(s_cm[i] - cmax);
    float top_cat_val = 1.0f / csum;

    // rank of this thread's prob among all 128 (descending, stable)
    int rank = 0;
    #pragma unroll 8
    for (int j = 0; j < NUM_NUM; ++j) {
        float pj = s_p[j];
        rank += (pj > p) || (pj == p && j < tid);
    }
    if (rank < N_ARY) {
        hdr_i[rank] = NUM_CAT + tid;
        hdr_f[32 + rank] = 0.5f * (p + top_cat_val);
    }
    if (tid == 0) hdr_i[64] = cidx;
}

// Pass 1: seg per row -> segc; histogram into cnt (1M atomics, L2-resident 400KB).
__global__ void hist_kernel(const int* __restrict__ idx,
                            const int* __restrict__ hdr_i,
                            int* __restrict__ segc,
                            int* __restrict__ cnt) {
    const int topcat = hdr_i[64];
    int r = blockIdx.x * blockDim.x + threadIdx.x;
    const int stride = gridDim.x * blockDim.x;
    for (; r < N_ROWS; r += stride) {
        int seg = idx[r * NUM_CAT + topcat];
        segc[r] = seg;
        atomicAdd(&cnt[seg], 1);
    }
}

// Pass 2: exclusive prefix sum over cnt -> ofs. Single block, 1024 threads,
// each owns a 98-element chunk; Hillis-Steele block scan over chunk sums.
#define SCAN_T 1024
#define SCAN_CHUNK 98   // 1024*98 = 100352 >= 100000
__global__ void scan_kernel(const int* __restrict__ cnt,
                            int* __restrict__ ofs) {
    __shared__ int s[SCAN_T];
    const int t = threadIdx.x;
    const int lo = t * SCAN_CHUNK;
    int hi = lo + SCAN_CHUNK; if (hi > NUM_SEG) hi = NUM_SEG;
    int sum = 0;
    for (int i = lo; i < hi; ++i) sum += cnt[i];
    s[t] = sum;
    __syncthreads();
    for (int d = 1; d < SCAN_T; d <<= 1) {
        int v = 0;
        if (t >= d) v = s[t - d];
        __syncthreads();
        if (t >= d) s[t] += v;
        __syncthreads();
    }
    int run = (t > 0) ? s[t - 1] : 0;        // exclusive offset of this chunk
    for (int i = lo; i < hi; ++i) {
        ofs[i] = run;
        run += cnt[i];
    }
}

// Pass 3: scatter row ids into seg-grouped order[] (1M atomics, L2-resident).
// After this, ofs[seg] == END of the seg's range (start = end - cnt[seg]).
__global__ void place_kernel(const int* __restrict__ segc,
                             int* __restrict__ ofs,
                             int* __restrict__ order) {
    int r = blockIdx.x * blockDim.x + threadIdx.x;
    const int stride = gridDim.x * blockDim.x;
    for (; r < N_ROWS; r += stride) {
        int seg = segc[r];
        int pos = atomicAdd(&ofs[seg], 1);
        order[pos] = r;
    }
}

// Pass 4: one HALF-WAVE per seg (lane j = column j). Sum the seg's rows with
// zero atomics, then scatter the per-seg result vector to every row's out
// line (out[row] = agg[seg]*conf -- identical for all rows of the seg).
// Deletes agg buffer + memset + transpose + gather entirely.
#define SEGS_PER_BLOCK 8   // 256 threads = 4 waves = 8 half-waves
__global__ void reduce_scatter_kernel(const float* __restrict__ inputs,
                                      const int* __restrict__ order,
                                      const int* __restrict__ cnt,
                                      const int* __restrict__ ofs_end,
                                      const int* __restrict__ hdr_i,
                                      const float* __restrict__ hdr_f,
                                      float* __restrict__ out) {
    const int seg = blockIdx.x * SEGS_PER_BLOCK + (threadIdx.x >> 5);
    const int j = threadIdx.x & 31;
    const int col = hdr_i[j];
    const float cf = hdr_f[32 + j];
    const int end = ofs_end[seg];
    const int n = cnt[seg];
    const int start = end - n;
    float acc = 0.f;
    for (int r = 0; r < n; ++r) {
        int row = order[start + r];          // same addr across 32 lanes: broadcast
        acc += inputs[row * NUM_ATTR + col];
    }
    const float ov = acc * cf;
    for (int r = 0; r < n; ++r) {
        int row = order[start + r];
        out[row * 32 + j] = ov;              // coalesced 128 B line per half-wave
    }
}

extern "C" void kernel_launch(void* const* d_in, const int* in_sizes, int n_in,
                              void* d_out, int out_size, void* d_ws, size_t ws_size,
                              hipStream_t stream) {
    const float* inputs   = (const float*)d_in[0];   // (1M, 144) f32
    const int*   idx      = (const int*)d_in[1];     // (1M, 16) int
    const float* cat_mask = (const float*)d_in[2];   // (16,)
    const float* num_mask = (const float*)d_in[3];   // (128,)
    float* out = (float*)d_out;                      // (1M, 32) f32

    int*   hdr_i = (int*)d_ws;
    float* hdr_f = (float*)d_ws;
    int*   cnt   = (int*)((char*)d_ws + CNT_OFFSET);
    int*   ofs   = (int*)((char*)d_ws + OFS_OFFSET);
    int*   segc  = (int*)((char*)d_ws + SEGC_OFFSET);
    int*   order = (int*)((char*)d_ws + ORDER_OFFSET);

    // 1) mask math -> header
    setup_kernel<<<1, 128, 0, stream>>>(cat_mask, num_mask, hdr_i, hdr_f);

    // 2) zero histogram (memset node is graph-capture safe)
    hipMemsetAsync(cnt, 0, (size_t)NUM_SEG * sizeof(int), stream);

    // 3) seg per row + histogram
    hist_kernel<<<2048, 256, 0, stream>>>(idx, hdr_i, segc, cnt);

    // 4) exclusive prefix sum
    scan_kernel<<<1, SCAN_T, 0, stream>>>(cnt, ofs);

    // 5) group row ids by seg
    place_kernel<<<2048, 256, 0, stream>>>(segc, ofs, order);

    // 6) per-seg reduction + direct scatter of scaled result to out
    reduce_scatter_kernel<<<NUM_SEG / SEGS_PER_BLOCK, 256, 0, stream>>>(
        inputs, order, cnt, ofs, hdr_i, hdr_f, out);
}